// Round 11
// baseline (108.179 us; speedup 1.0000x reference)
//
#include <hip/hip_runtime.h>
#include <math.h>

#define N_TOK 1024
#define C_DIM 384
#define H_NUM 12
#define PCOLS 1024
#define Q0 0
#define K0 192
#define V0 384
#define QP0 576
#define KP0 720
#define VP0 864
#define ATT_W 240
#define COEF 0.11785113019775792f   // 0.5*sqrt(2/36)
#define ISD 0.25f
#define CC2 (COEF * ISD)            // 0.029462...
#define KV_ROWS 60
#define NZ 4

// ---------- pack 6 weight mats into Wall[384][1024] (cols 1008..1023 zero) ----------
__global__ __launch_bounds__(256) void k_pack(
    const float* __restrict__ Wq, const float* __restrict__ Wk, const float* __restrict__ Wv,
    const float* __restrict__ Wqp, const float* __restrict__ Wkp, const float* __restrict__ Wvp,
    float* __restrict__ Wall)
{
    int t = blockIdx.x * 256 + threadIdx.x;
    int k = t >> 8;
    int col = (t & 255) * 4;
    float4 v;
    if (col < 192)       v = *(const float4*)(Wq  + k * 192 + col);
    else if (col < 384)  v = *(const float4*)(Wk  + k * 192 + col - 192);
    else if (col < 576)  v = *(const float4*)(Wv  + k * 192 + col - 384);
    else if (col < 720)  v = *(const float4*)(Wqp + k * 144 + col - 576);
    else if (col < 864)  v = *(const float4*)(Wkp + k * 144 + col - 720);
    else if (col < 1008) v = *(const float4*)(Wvp + k * 144 + col - 864);
    else                 v = make_float4(0.f, 0.f, 0.f, 0.f);
    *(float4*)(Wall + k * PCOLS + col) = v;
}

// ---------- proj GEMM, no-LDS register pipeline ----------
// grid (16,16), 256 thr (16 ty x 16 tx). Thread: 4 rows x 4 cols, k-quad pipelined.
__global__ __launch_bounds__(256, 1) void k_proj(
    const float* __restrict__ x, const float* __restrict__ Wall, float* __restrict__ P)
{
    int tid = threadIdx.x;
    int ty = tid >> 4, tx = tid & 15;
    int row0 = blockIdx.x * 64 + ty * 4;
    int col0 = blockIdx.y * 64 + tx * 4;
    const float* xr = x + row0 * C_DIM;
    const float* wp = Wall + col0;

    float acc[4][4] = {};
    float A[4][4], B[4][4], An[4][4], Bn[4][4];

#pragma unroll
    for (int r = 0; r < 4; ++r) *(float4*)A[r] = *(const float4*)(xr + r * C_DIM);
#pragma unroll
    for (int u = 0; u < 4; ++u) *(float4*)B[u] = *(const float4*)(wp + u * PCOLS);

#define PROJ_FMA(AA, BB)                                                      \
    _Pragma("unroll")                                                         \
    for (int u = 0; u < 4; ++u) {                                             \
        _Pragma("unroll")                                                     \
        for (int r = 0; r < 4; ++r) {                                         \
            _Pragma("unroll")                                                 \
            for (int c = 0; c < 4; ++c)                                       \
                acc[r][c] = fmaf(AA[r][u], BB[u][c], acc[r][c]);              \
        }                                                                     \
    }

    for (int q = 0; q < 96; q += 2) {
        int k1 = (q + 1) * 4;
#pragma unroll
        for (int r = 0; r < 4; ++r) *(float4*)An[r] = *(const float4*)(xr + r * C_DIM + k1);
#pragma unroll
        for (int u = 0; u < 4; ++u) *(float4*)Bn[u] = *(const float4*)(wp + (k1 + u) * PCOLS);
        PROJ_FMA(A, B);
        if (q + 2 < 96) {
            int k2 = (q + 2) * 4;
#pragma unroll
            for (int r = 0; r < 4; ++r) *(float4*)A[r] = *(const float4*)(xr + r * C_DIM + k2);
#pragma unroll
            for (int u = 0; u < 4; ++u) *(float4*)B[u] = *(const float4*)(wp + (k2 + u) * PCOLS);
        }
        PROJ_FMA(An, Bn);
    }
#pragma unroll
    for (int r = 0; r < 4; ++r)
        *(float4*)(P + (row0 + r) * PCOLS + col0) =
            make_float4(acc[r][0], acc[r][1], acc[r][2], acc[r][3]);
}

// ---------- prep: build d-major Q'[h][29][1024], KV'[h][60][1024], qc[h][1024] ----------
__global__ __launch_bounds__(256) void k_prep(
    const float* __restrict__ P, const float* __restrict__ rot, const float* __restrict__ trans,
    float* __restrict__ KVg, float* __restrict__ Qg, float* __restrict__ qcg)
{
    __shared__ float kb[29 * 128];
    __shared__ float qb[29 * 128];
    __shared__ float vb[28 * 128];
    __shared__ float qcb[128];
    int h = blockIdx.y, nb = blockIdx.x;
    int tid = threadIdx.x;
    int nl = tid & 127, role = tid >> 7;
    int n = nb * 128 + nl;
    const float* R = rot + n * 9;
    float R00 = R[0], R01 = R[1], R02 = R[2];
    float R10 = R[3], R11 = R[4], R12 = R[5];
    float R20 = R[6], R21 = R[7], R22 = R[8];
    float t0 = trans[n * 3 + 0], t1 = trans[n * 3 + 1], t2 = trans[n * 3 + 2];

    if (role == 0) {
        const float* kr = P + n * PCOLS + K0 + h * 16;
#pragma unroll
        for (int d = 0; d < 16; ++d) kb[d * 128 + nl] = kr[d];
        const float* kp = P + n * PCOLS + KP0 + h * 12;
        float k2 = 0.f;
#pragma unroll
        for (int pt = 0; pt < 4; ++pt) {
            float p0 = kp[pt * 3 + 0], p1 = kp[pt * 3 + 1], p2 = kp[pt * 3 + 2];
            float g0 = R00 * p0 + R01 * p1 + R02 * p2 + t0;
            float g1 = R10 * p0 + R11 * p1 + R12 * p2 + t1;
            float g2 = R20 * p0 + R21 * p1 + R22 * p2 + t2;
            kb[(16 + pt * 3 + 0) * 128 + nl] = g0;
            kb[(16 + pt * 3 + 1) * 128 + nl] = g1;
            kb[(16 + pt * 3 + 2) * 128 + nl] = g2;
            k2 += g0 * g0 + g1 * g1 + g2 * g2;
        }
        kb[28 * 128 + nl] = -CC2 * k2;
    } else {
        const float* qr = P + n * PCOLS + Q0 + h * 16;
#pragma unroll
        for (int d = 0; d < 16; ++d) qb[d * 128 + nl] = qr[d] * ISD;
        const float* qp = P + n * PCOLS + QP0 + h * 12;
        float q2 = 0.f;
#pragma unroll
        for (int pt = 0; pt < 4; ++pt) {
            float p0 = qp[pt * 3 + 0], p1 = qp[pt * 3 + 1], p2 = qp[pt * 3 + 2];
            float g0 = R00 * p0 + R01 * p1 + R02 * p2 + t0;
            float g1 = R10 * p0 + R11 * p1 + R12 * p2 + t1;
            float g2 = R20 * p0 + R21 * p1 + R22 * p2 + t2;
            qb[(16 + pt * 3 + 0) * 128 + nl] = g0 * (2.f * CC2);
            qb[(16 + pt * 3 + 1) * 128 + nl] = g1 * (2.f * CC2);
            qb[(16 + pt * 3 + 2) * 128 + nl] = g2 * (2.f * CC2);
            q2 += g0 * g0 + g1 * g1 + g2 * g2;
        }
        qb[28 * 128 + nl] = 1.0f;
        qcb[nl] = fmaf(-CC2, q2, -4.0f);
        const float* vr = P + n * PCOLS + V0 + h * 16;
#pragma unroll
        for (int d = 0; d < 16; ++d) vb[d * 128 + nl] = vr[d];
        const float* vp = P + n * PCOLS + VP0 + h * 12;
#pragma unroll
        for (int pt = 0; pt < 4; ++pt) {
            float p0 = vp[pt * 3 + 0], p1 = vp[pt * 3 + 1], p2 = vp[pt * 3 + 2];
            vb[(16 + pt * 3 + 0) * 128 + nl] = R00 * p0 + R01 * p1 + R02 * p2 + t0;
            vb[(16 + pt * 3 + 1) * 128 + nl] = R10 * p0 + R11 * p1 + R12 * p2 + t1;
            vb[(16 + pt * 3 + 2) * 128 + nl] = R20 * p0 + R21 * p1 + R22 * p2 + t2;
        }
    }
    __syncthreads();

    for (int u = tid; u < 57 * 32; u += 256) {
        int d = u >> 5, c4 = u & 31;
        float4 v = (d < 29) ? *(float4*)&kb[d * 128 + c4 * 4]
                            : *(float4*)&vb[(d - 29) * 128 + c4 * 4];
        *(float4*)&KVg[(h * KV_ROWS + d) * 1024 + nb * 128 + c4 * 4] = v;
    }
    for (int u = tid; u < 29 * 32; u += 256) {
        int d = u >> 5, c4 = u & 31;
        *(float4*)&Qg[(h * 29 + d) * 1024 + nb * 128 + c4 * 4] = *(float4*)&qb[d * 128 + c4 * 4];
    }
    if (tid < 32) *(float4*)&qcg[h * 1024 + nb * 128 + tid * 4] = *(float4*)&qcb[tid * 4];
}

// ---------- attention as register-tiled GEMM, global_load_lds staging ----------
__global__ __launch_bounds__(256, 3) void k_attn(
    const float* __restrict__ KVg, const float* __restrict__ Qg,
    const float* __restrict__ qcg, float* __restrict__ part)
{
    __shared__ float Qs[29 * 64];
    __shared__ float KV[2][KV_ROWS * 64];
    int tid = threadIdx.x;
    int lane = tid & 63, w = tid >> 6;
    int ty = tid >> 3, tx = tid & 7;

    int bid = blockIdx.x;
    int xcd = bid & 7, slot = bid >> 3;
    int pair = xcd * 6 + (slot >> 4);     // 0..47
    int bx = slot & 15;
    int h = pair % H_NUM;
    int z = pair / H_NUM;

    int i0 = bx * 64;
    int jz0 = z * 256;
    const float* KVh = KVg + h * KV_ROWS * 1024;

    for (int u = tid; u < 29 * 16; u += 256) {
        int d = u >> 4, c4 = u & 15;
        *(float4*)&Qs[d * 64 + c4 * 4] = *(const float4*)&Qg[(h * 29 + d) * 1024 + i0 + c4 * 4];
    }
    float qc[2];
#pragma unroll
    for (int r = 0; r < 2; ++r) qc[r] = qcg[h * 1024 + i0 + ty * 2 + r];

    int nst = (w < 3) ? 4 : 3;
#define STAGE(T) do { float* buf_ = KV[(T) & 1]; int j0_ = jz0 + (T) * 64;        \
        for (int m_ = 0; m_ < nst; ++m_) {                                        \
            int g_ = w * 4 + m_;                                                  \
            const float* src_ = KVh + (g_ * 4 + (lane >> 4)) * 1024 + j0_ + (lane & 15) * 4; \
            float* dst_ = buf_ + g_ * 256;                                        \
            __builtin_amdgcn_global_load_lds(                                     \
                (const __attribute__((address_space(1))) void*)src_,              \
                (__attribute__((address_space(3))) void*)dst_, 16, 0, 0);         \
        } } while (0)

    STAGE(0);
    __syncthreads();

    float out[2][28] = {};
    float denom[2] = {};

    for (int t = 0; t < 4; ++t) {
        if (t < 3) STAGE(t + 1);
        const float* Kb = KV[t & 1];
        const float* Vb = Kb + 29 * 64;

        float s[2][8] = {};
#pragma unroll
        for (int d = 0; d < 29; ++d) {
            float2 qv = *(const float2*)&Qs[d * 64 + ty * 2];
            float4 k0 = *(const float4*)&Kb[d * 64 + tx * 8];
            float4 k1 = *(const float4*)&Kb[d * 64 + tx * 8 + 4];
            float ka[8] = {k0.x, k0.y, k0.z, k0.w, k1.x, k1.y, k1.z, k1.w};
#pragma unroll
            for (int j = 0; j < 8; ++j) {
                s[0][j] = fmaf(qv.x, ka[j], s[0][j]);
                s[1][j] = fmaf(qv.y, ka[j], s[1][j]);
            }
        }

        float p[2][8];
#pragma unroll
        for (int r = 0; r < 2; ++r) {
#pragma unroll
            for (int j = 0; j < 8; ++j) {
                p[r][j] = __expf(s[r][j] + qc[r]);
                denom[r] += p[r][j];
            }
        }

#pragma unroll
        for (int d = 0; d < 28; ++d) {
            float4 v0 = *(const float4*)&Vb[d * 64 + tx * 8];
            float4 v1 = *(const float4*)&Vb[d * 64 + tx * 8 + 4];
            float va[8] = {v0.x, v0.y, v0.z, v0.w, v1.x, v1.y, v1.z, v1.w};
#pragma unroll
            for (int r = 0; r < 2; ++r) {
                float acc = out[r][d];
#pragma unroll
                for (int j = 0; j < 8; ++j) acc = fmaf(p[r][j], va[j], acc);
                out[r][d] = acc;
            }
        }
        __syncthreads();
    }

#pragma unroll
    for (int m = 1; m <= 4; m <<= 1) {
#pragma unroll
        for (int r = 0; r < 2; ++r) {
#pragma unroll
            for (int d = 0; d < 28; ++d) out[r][d] += __shfl_xor(out[r][d], m, 64);
            denom[r] += __shfl_xor(denom[r], m, 64);
        }
    }
    if (tx == 0) {
#pragma unroll
        for (int r = 0; r < 2; ++r) {
#pragma unroll
            for (int d = 0; d < 28; ++d) Qs[d * 64 + ty * 2 + r] = out[r][d];
            Qs[28 * 64 + ty * 2 + r] = denom[r];
        }
    }
    __syncthreads();
    for (int u = tid; u < 29 * 64; u += 256) {
        part[((z * H_NUM + h) * 29 + (u >> 6)) * N_TOK + i0 + (u & 63)] = Qs[u];
    }
}

// ---------- combine 4 partials, normalize, point-norm epilogue ----------
__global__ __launch_bounds__(256) void k_comb(
    const float* __restrict__ part, const float* __restrict__ rot,
    const float* __restrict__ trans, float* __restrict__ att)
{
    int t = blockIdx.x * 256 + threadIdx.x;
    int h = t >> 10, i = t & 1023;
    float v[29];
#pragma unroll
    for (int c = 0; c < 29; ++c) {
        float s = 0.f;
#pragma unroll
        for (int z = 0; z < NZ; ++z)
            s += part[((z * H_NUM + h) * 29 + c) * N_TOK + i];
        v[c] = s;
    }
    float inv = 1.f / v[28];
    float* arow = att + i * ATT_W;
#pragma unroll
    for (int d = 0; d < 16; ++d) arow[h * 16 + d] = v[d] * inv;
    float t0 = trans[i * 3 + 0], t1 = trans[i * 3 + 1], t2v = trans[i * 3 + 2];
    const float* R = rot + i * 9;
#pragma unroll
    for (int p = 0; p < 4; ++p) {
        float c0 = v[16 + p * 3 + 0] * inv - t0;
        float c1 = v[16 + p * 3 + 1] * inv - t1;
        float c2 = v[16 + p * 3 + 2] * inv - t2v;
        float l0 = R[0] * c0 + R[3] * c1 + R[6] * c2;
        float l1 = R[1] * c0 + R[4] * c1 + R[7] * c2;
        float l2 = R[2] * c0 + R[5] * c1 + R[8] * c2;
        arow[192 + h * 4 + p] = sqrtf(l0 * l0 + l1 * l1 + l2 * l2);
    }
}

// ---------- out GEMM, no-LDS register pipeline ----------
// grid (64,6), 256 thr (16 ty x 16 tx). Thread: 1 row x 4 cols, k-quad pipelined.
__global__ __launch_bounds__(256, 1) void k_out(
    const float* __restrict__ att, const float* __restrict__ Wout,
    const float* __restrict__ bout, float* __restrict__ out)
{
    int tid = threadIdx.x;
    int ty = tid >> 4, tx = tid & 15;
    int row = blockIdx.x * 16 + ty;
    int col0 = blockIdx.y * 64 + tx * 4;
    const float* ar = att + row * ATT_W;
    const float* wp = Wout + col0;

    float acc[4] = {};
    float A[4], B[4][4], An[4], Bn[4][4];

    *(float4*)A = *(const float4*)ar;
#pragma unroll
    for (int u = 0; u < 4; ++u) *(float4*)B[u] = *(const float4*)(wp + u * C_DIM);

#define OUT_FMA(AA, BB)                                                       \
    _Pragma("unroll")                                                         \
    for (int u = 0; u < 4; ++u) {                                             \
        _Pragma("unroll")                                                     \
        for (int c = 0; c < 4; ++c)                                           \
            acc[c] = fmaf(AA[u], BB[u][c], acc[c]);                           \
    }

    for (int q = 0; q < 60; q += 2) {
        int k1 = (q + 1) * 4;
        *(float4*)An = *(const float4*)(ar + k1);
#pragma unroll
        for (int u = 0; u < 4; ++u) *(float4*)Bn[u] = *(const float4*)(wp + (k1 + u) * C_DIM);
        OUT_FMA(A, B);
        if (q + 2 < 60) {
            int k2 = (q + 2) * 4;
            *(float4*)A = *(const float4*)(ar + k2);
#pragma unroll
            for (int u = 0; u < 4; ++u) *(float4*)B[u] = *(const float4*)(wp + (k2 + u) * C_DIM);
        }
        OUT_FMA(An, Bn);
    }
    float4 bb = *(const float4*)(bout + col0);
    *(float4*)(out + row * C_DIM + col0) =
        make_float4(acc[0] + bb.x, acc[1] + bb.y, acc[2] + bb.z, acc[3] + bb.w);
}

extern "C" void kernel_launch(void* const* d_in, const int* in_sizes, int n_in,
                              void* d_out, int out_size, void* d_ws, size_t ws_size,
                              hipStream_t stream) {
    const float* x     = (const float*)d_in[0];
    const float* rot   = (const float*)d_in[1];
    const float* trans = (const float*)d_in[2];
    const float* Wq    = (const float*)d_in[3];
    const float* Wk    = (const float*)d_in[4];
    const float* Wv    = (const float*)d_in[5];
    const float* Wqp   = (const float*)d_in[6];
    const float* Wkp   = (const float*)d_in[7];
    const float* Wvp   = (const float*)d_in[8];
    const float* Wout  = (const float*)d_in[9];
    const float* bout  = (const float*)d_in[10];
    float* out = (float*)d_out;

    float* ws = (float*)d_ws;
    float* Wall = ws;                            // 384*1024
    float* P    = Wall + C_DIM * PCOLS;          // 1024*1024
    float* KVg  = P    + N_TOK * PCOLS;          // 12*60*1024
    float* Qg   = KVg  + H_NUM * KV_ROWS * 1024; // 12*29*1024
    float* qcg  = Qg   + H_NUM * 29 * 1024;      // 12*1024
    float* part = ws;                            // alias Wall+P
    float* att  = Qg;                            // alias Qg (dead after k_attn)

    k_pack<<<384, 256, 0, stream>>>(Wq, Wk, Wv, Wqp, Wkp, Wvp, Wall);
    k_proj<<<dim3(16, 16), 256, 0, stream>>>(x, Wall, P);
    k_prep<<<dim3(8, 12), 256, 0, stream>>>(P, rot, trans, KVg, Qg, qcg);
    k_attn<<<768, 256, 0, stream>>>(KVg, Qg, qcg, part);
    k_comb<<<48, 256, 0, stream>>>(part, rot, trans, att);
    k_out<<<dim3(64, 6), 256, 0, stream>>>(att, Wout, bout, out);
}

// Round 12
// 100.215 us; speedup vs baseline: 1.0795x; 1.0795x over previous
//
#include <hip/hip_runtime.h>
#include <math.h>

#define N_TOK 1024
#define C_DIM 384
#define H_NUM 12
#define PCOLS 1024
#define Q0 0
#define K0 192
#define V0 384
#define QP0 576
#define KP0 720
#define VP0 864
#define ATT_W 240
#define COEF 0.11785113019775792f   // 0.5*sqrt(2/36)
#define ISD 0.25f
#define CC2 (COEF * ISD)            // 0.029462...
#define KV_ROWS 60
#define NZ 4

// ---------- pack 6 weight mats into Wall[384][1024] (cols 1008..1023 zero) ----------
__global__ __launch_bounds__(256) void k_pack(
    const float* __restrict__ Wq, const float* __restrict__ Wk, const float* __restrict__ Wv,
    const float* __restrict__ Wqp, const float* __restrict__ Wkp, const float* __restrict__ Wvp,
    float* __restrict__ Wall)
{
    int t = blockIdx.x * 256 + threadIdx.x;
    int k = t >> 8;
    int col = (t & 255) * 4;
    float4 v;
    if (col < 192)       v = *(const float4*)(Wq  + k * 192 + col);
    else if (col < 384)  v = *(const float4*)(Wk  + k * 192 + col - 192);
    else if (col < 576)  v = *(const float4*)(Wv  + k * 192 + col - 384);
    else if (col < 720)  v = *(const float4*)(Wqp + k * 144 + col - 576);
    else if (col < 864)  v = *(const float4*)(Wkp + k * 144 + col - 720);
    else if (col < 1008) v = *(const float4*)(Wvp + k * 144 + col - 864);
    else                 v = make_float4(0.f, 0.f, 0.f, 0.f);
    *(float4*)(Wall + k * PCOLS + col) = v;
}

// ---------- proj GEMM: hybrid (A global/L1-broadcast, B LDS double-buffered) ----------
// grid (16,16), 256 thr (16 ty x 16 tx). Thread: 4 rows x 4 cols, BK=16.
__global__ __launch_bounds__(256) void k_proj(
    const float* __restrict__ x, const float* __restrict__ Wall, float* __restrict__ P)
{
    __shared__ float wsh[2][16][64];
    int tid = threadIdx.x;
    int ty = tid >> 4, tx = tid & 15;
    int wr = tid >> 4, wc = (tid & 15) * 4;
    int row0 = blockIdx.x * 64 + ty * 4;
    int col0 = blockIdx.y * 64;
    const float* xr = x + row0 * C_DIM;

    float acc[4][4] = {};
    {
        float4 w0 = *(const float4*)(Wall + wr * PCOLS + col0 + wc);
        *(float4*)&wsh[0][wr][wc] = w0;
    }
    __syncthreads();

    for (int it = 0; it < 24; ++it) {
        float4 Ar[4][4];
#pragma unroll
        for (int r = 0; r < 4; ++r)
#pragma unroll
            for (int q = 0; q < 4; ++q)
                Ar[r][q] = *(const float4*)(xr + r * C_DIM + it * 16 + q * 4);
        if (it < 23) {
            float4 wn = *(const float4*)(Wall + ((it + 1) * 16 + wr) * PCOLS + col0 + wc);
            *(float4*)&wsh[(it + 1) & 1][wr][wc] = wn;
        }
        const float (*wb)[64] = wsh[it & 1];
#pragma unroll
        for (int q = 0; q < 4; ++q) {
#pragma unroll
            for (int u = 0; u < 4; ++u) {
                float4 b = *(const float4*)&wb[q * 4 + u][tx * 4];
#pragma unroll
                for (int r = 0; r < 4; ++r) {
                    float a = (u == 0) ? Ar[r][q].x : (u == 1) ? Ar[r][q].y
                             : (u == 2) ? Ar[r][q].z : Ar[r][q].w;
                    acc[r][0] = fmaf(a, b.x, acc[r][0]);
                    acc[r][1] = fmaf(a, b.y, acc[r][1]);
                    acc[r][2] = fmaf(a, b.z, acc[r][2]);
                    acc[r][3] = fmaf(a, b.w, acc[r][3]);
                }
            }
        }
        __syncthreads();
    }
#pragma unroll
    for (int r = 0; r < 4; ++r)
        *(float4*)(P + (row0 + r) * PCOLS + col0 + tx * 4) =
            make_float4(acc[r][0], acc[r][1], acc[r][2], acc[r][3]);
}

// ---------- prep: build d-major Q'[h][29][1024], KV'[h][60][1024], qc[h][1024] ----------
__global__ __launch_bounds__(256) void k_prep(
    const float* __restrict__ P, const float* __restrict__ rot, const float* __restrict__ trans,
    float* __restrict__ KVg, float* __restrict__ Qg, float* __restrict__ qcg)
{
    __shared__ float kb[29 * 128];
    __shared__ float qb[29 * 128];
    __shared__ float vb[28 * 128];
    __shared__ float qcb[128];
    int h = blockIdx.y, nb = blockIdx.x;
    int tid = threadIdx.x;
    int nl = tid & 127, role = tid >> 7;
    int n = nb * 128 + nl;
    const float* R = rot + n * 9;
    float R00 = R[0], R01 = R[1], R02 = R[2];
    float R10 = R[3], R11 = R[4], R12 = R[5];
    float R20 = R[6], R21 = R[7], R22 = R[8];
    float t0 = trans[n * 3 + 0], t1 = trans[n * 3 + 1], t2 = trans[n * 3 + 2];

    if (role == 0) {
        const float* kr = P + n * PCOLS + K0 + h * 16;
#pragma unroll
        for (int d = 0; d < 16; ++d) kb[d * 128 + nl] = kr[d];
        const float* kp = P + n * PCOLS + KP0 + h * 12;
        float k2 = 0.f;
#pragma unroll
        for (int pt = 0; pt < 4; ++pt) {
            float p0 = kp[pt * 3 + 0], p1 = kp[pt * 3 + 1], p2 = kp[pt * 3 + 2];
            float g0 = R00 * p0 + R01 * p1 + R02 * p2 + t0;
            float g1 = R10 * p0 + R11 * p1 + R12 * p2 + t1;
            float g2 = R20 * p0 + R21 * p1 + R22 * p2 + t2;
            kb[(16 + pt * 3 + 0) * 128 + nl] = g0;
            kb[(16 + pt * 3 + 1) * 128 + nl] = g1;
            kb[(16 + pt * 3 + 2) * 128 + nl] = g2;
            k2 += g0 * g0 + g1 * g1 + g2 * g2;
        }
        kb[28 * 128 + nl] = -CC2 * k2;
    } else {
        const float* qr = P + n * PCOLS + Q0 + h * 16;
#pragma unroll
        for (int d = 0; d < 16; ++d) qb[d * 128 + nl] = qr[d] * ISD;
        const float* qp = P + n * PCOLS + QP0 + h * 12;
        float q2 = 0.f;
#pragma unroll
        for (int pt = 0; pt < 4; ++pt) {
            float p0 = qp[pt * 3 + 0], p1 = qp[pt * 3 + 1], p2 = qp[pt * 3 + 2];
            float g0 = R00 * p0 + R01 * p1 + R02 * p2 + t0;
            float g1 = R10 * p0 + R11 * p1 + R12 * p2 + t1;
            float g2 = R20 * p0 + R21 * p1 + R22 * p2 + t2;
            qb[(16 + pt * 3 + 0) * 128 + nl] = g0 * (2.f * CC2);
            qb[(16 + pt * 3 + 1) * 128 + nl] = g1 * (2.f * CC2);
            qb[(16 + pt * 3 + 2) * 128 + nl] = g2 * (2.f * CC2);
            q2 += g0 * g0 + g1 * g1 + g2 * g2;
        }
        qb[28 * 128 + nl] = 1.0f;
        qcb[nl] = fmaf(-CC2, q2, -4.0f);
        const float* vr = P + n * PCOLS + V0 + h * 16;
#pragma unroll
        for (int d = 0; d < 16; ++d) vb[d * 128 + nl] = vr[d];
        const float* vp = P + n * PCOLS + VP0 + h * 12;
#pragma unroll
        for (int pt = 0; pt < 4; ++pt) {
            float p0 = vp[pt * 3 + 0], p1 = vp[pt * 3 + 1], p2 = vp[pt * 3 + 2];
            vb[(16 + pt * 3 + 0) * 128 + nl] = R00 * p0 + R01 * p1 + R02 * p2 + t0;
            vb[(16 + pt * 3 + 1) * 128 + nl] = R10 * p0 + R11 * p1 + R12 * p2 + t1;
            vb[(16 + pt * 3 + 2) * 128 + nl] = R20 * p0 + R21 * p1 + R22 * p2 + t2;
        }
    }
    __syncthreads();

    for (int u = tid; u < 57 * 32; u += 256) {
        int d = u >> 5, c4 = u & 31;
        float4 v = (d < 29) ? *(float4*)&kb[d * 128 + c4 * 4]
                            : *(float4*)&vb[(d - 29) * 128 + c4 * 4];
        *(float4*)&KVg[(h * KV_ROWS + d) * 1024 + nb * 128 + c4 * 4] = v;
    }
    for (int u = tid; u < 29 * 32; u += 256) {
        int d = u >> 5, c4 = u & 31;
        *(float4*)&Qg[(h * 29 + d) * 1024 + nb * 128 + c4 * 4] = *(float4*)&qb[d * 128 + c4 * 4];
    }
    if (tid < 32) *(float4*)&qcg[h * 1024 + nb * 128 + tid * 4] = *(float4*)&qcb[tid * 4];
}

// ---------- attention as register-tiled GEMM, global_load_lds staging ----------
__global__ __launch_bounds__(256, 3) void k_attn(
    const float* __restrict__ KVg, const float* __restrict__ Qg,
    const float* __restrict__ qcg, float* __restrict__ part)
{
    __shared__ float Qs[29 * 64];
    __shared__ float KV[2][KV_ROWS * 64];
    int tid = threadIdx.x;
    int lane = tid & 63, w = tid >> 6;
    int ty = tid >> 3, tx = tid & 7;

    int bid = blockIdx.x;
    int xcd = bid & 7, slot = bid >> 3;
    int pair = xcd * 6 + (slot >> 4);     // 0..47
    int bx = slot & 15;
    int h = pair % H_NUM;
    int z = pair / H_NUM;

    int i0 = bx * 64;
    int jz0 = z * 256;
    const float* KVh = KVg + h * KV_ROWS * 1024;

    for (int u = tid; u < 29 * 16; u += 256) {
        int d = u >> 4, c4 = u & 15;
        *(float4*)&Qs[d * 64 + c4 * 4] = *(const float4*)&Qg[(h * 29 + d) * 1024 + i0 + c4 * 4];
    }
    float qc[2];
#pragma unroll
    for (int r = 0; r < 2; ++r) qc[r] = qcg[h * 1024 + i0 + ty * 2 + r];

    int nst = (w < 3) ? 4 : 3;
#define STAGE(T) do { float* buf_ = KV[(T) & 1]; int j0_ = jz0 + (T) * 64;        \
        for (int m_ = 0; m_ < nst; ++m_) {                                        \
            int g_ = w * 4 + m_;                                                  \
            const float* src_ = KVh + (g_ * 4 + (lane >> 4)) * 1024 + j0_ + (lane & 15) * 4; \
            float* dst_ = buf_ + g_ * 256;                                        \
            __builtin_amdgcn_global_load_lds(                                     \
                (const __attribute__((address_space(1))) void*)src_,              \
                (__attribute__((address_space(3))) void*)dst_, 16, 0, 0);         \
        } } while (0)

    STAGE(0);
    __syncthreads();

    float out[2][28] = {};
    float denom[2] = {};

    for (int t = 0; t < 4; ++t) {
        if (t < 3) STAGE(t + 1);
        const float* Kb = KV[t & 1];
        const float* Vb = Kb + 29 * 64;

        float s[2][8] = {};
#pragma unroll
        for (int d = 0; d < 29; ++d) {
            float2 qv = *(const float2*)&Qs[d * 64 + ty * 2];
            float4 k0 = *(const float4*)&Kb[d * 64 + tx * 8];
            float4 k1 = *(const float4*)&Kb[d * 64 + tx * 8 + 4];
            float ka[8] = {k0.x, k0.y, k0.z, k0.w, k1.x, k1.y, k1.z, k1.w};
#pragma unroll
            for (int j = 0; j < 8; ++j) {
                s[0][j] = fmaf(qv.x, ka[j], s[0][j]);
                s[1][j] = fmaf(qv.y, ka[j], s[1][j]);
            }
        }

        float p[2][8];
#pragma unroll
        for (int r = 0; r < 2; ++r) {
#pragma unroll
            for (int j = 0; j < 8; ++j) {
                p[r][j] = __expf(s[r][j] + qc[r]);
                denom[r] += p[r][j];
            }
        }

#pragma unroll
        for (int d = 0; d < 28; ++d) {
            float4 v0 = *(const float4*)&Vb[d * 64 + tx * 8];
            float4 v1 = *(const float4*)&Vb[d * 64 + tx * 8 + 4];
            float va[8] = {v0.x, v0.y, v0.z, v0.w, v1.x, v1.y, v1.z, v1.w};
#pragma unroll
            for (int r = 0; r < 2; ++r) {
                float acc = out[r][d];
#pragma unroll
                for (int j = 0; j < 8; ++j) acc = fmaf(p[r][j], va[j], acc);
                out[r][d] = acc;
            }
        }
        __syncthreads();
    }

#pragma unroll
    for (int m = 1; m <= 4; m <<= 1) {
#pragma unroll
        for (int r = 0; r < 2; ++r) {
#pragma unroll
            for (int d = 0; d < 28; ++d) out[r][d] += __shfl_xor(out[r][d], m, 64);
            denom[r] += __shfl_xor(denom[r], m, 64);
        }
    }
    if (tx == 0) {
#pragma unroll
        for (int r = 0; r < 2; ++r) {
#pragma unroll
            for (int d = 0; d < 28; ++d) Qs[d * 64 + ty * 2 + r] = out[r][d];
            Qs[28 * 64 + ty * 2 + r] = denom[r];
        }
    }
    __syncthreads();
    for (int u = tid; u < 29 * 64; u += 256) {
        part[((z * H_NUM + h) * 29 + (u >> 6)) * N_TOK + i0 + (u & 63)] = Qs[u];
    }
}

// ---------- combine 4 partials, normalize, point-norm epilogue ----------
__global__ __launch_bounds__(256) void k_comb(
    const float* __restrict__ part, const float* __restrict__ rot,
    const float* __restrict__ trans, float* __restrict__ att)
{
    int t = blockIdx.x * 256 + threadIdx.x;
    int h = t >> 10, i = t & 1023;
    float v[29];
#pragma unroll
    for (int c = 0; c < 29; ++c) {
        float s = 0.f;
#pragma unroll
        for (int z = 0; z < NZ; ++z)
            s += part[((z * H_NUM + h) * 29 + c) * N_TOK + i];
        v[c] = s;
    }
    float inv = 1.f / v[28];
    float* arow = att + i * ATT_W;
#pragma unroll
    for (int d = 0; d < 16; ++d) arow[h * 16 + d] = v[d] * inv;
    float t0 = trans[i * 3 + 0], t1 = trans[i * 3 + 1], t2v = trans[i * 3 + 2];
    const float* R = rot + i * 9;
#pragma unroll
    for (int p = 0; p < 4; ++p) {
        float c0 = v[16 + p * 3 + 0] * inv - t0;
        float c1 = v[16 + p * 3 + 1] * inv - t1;
        float c2 = v[16 + p * 3 + 2] * inv - t2v;
        float l0 = R[0] * c0 + R[3] * c1 + R[6] * c2;
        float l1 = R[1] * c0 + R[4] * c1 + R[7] * c2;
        float l2 = R[2] * c0 + R[5] * c1 + R[8] * c2;
        arow[192 + h * 4 + p] = sqrtf(l0 * l0 + l1 * l1 + l2 * l2);
    }
}

// ---------- out GEMM: hybrid (A global/L1-broadcast, B LDS double-buffered) ----------
// grid (32,6), 256 thr (16 ty x 16 tx). Thread: 2 rows x 4 cols, BK=16, K=240.
__global__ __launch_bounds__(256) void k_out(
    const float* __restrict__ att, const float* __restrict__ Wout,
    const float* __restrict__ bout, float* __restrict__ out)
{
    __shared__ float wsh[2][16][64];
    int tid = threadIdx.x;
    int ty = tid >> 4, tx = tid & 15;
    int wr = tid >> 4, wc = (tid & 15) * 4;
    int row0 = blockIdx.x * 32 + ty * 2;
    int col0 = blockIdx.y * 64;
    const float* ar = att + row0 * ATT_W;

    float acc[2][4] = {};
    {
        float4 w0 = *(const float4*)(Wout + wr * C_DIM + col0 + wc);
        *(float4*)&wsh[0][wr][wc] = w0;
    }
    __syncthreads();

    for (int it = 0; it < 15; ++it) {
        float4 Ar[2][4];
#pragma unroll
        for (int r = 0; r < 2; ++r)
#pragma unroll
            for (int q = 0; q < 4; ++q)
                Ar[r][q] = *(const float4*)(ar + r * ATT_W + it * 16 + q * 4);
        if (it < 14) {
            float4 wn = *(const float4*)(Wout + ((it + 1) * 16 + wr) * C_DIM + col0 + wc);
            *(float4*)&wsh[(it + 1) & 1][wr][wc] = wn;
        }
        const float (*wb)[64] = wsh[it & 1];
#pragma unroll
        for (int q = 0; q < 4; ++q) {
#pragma unroll
            for (int u = 0; u < 4; ++u) {
                float4 b = *(const float4*)&wb[q * 4 + u][tx * 4];
#pragma unroll
                for (int r = 0; r < 2; ++r) {
                    float a = (u == 0) ? Ar[r][q].x : (u == 1) ? Ar[r][q].y
                             : (u == 2) ? Ar[r][q].z : Ar[r][q].w;
                    acc[r][0] = fmaf(a, b.x, acc[r][0]);
                    acc[r][1] = fmaf(a, b.y, acc[r][1]);
                    acc[r][2] = fmaf(a, b.z, acc[r][2]);
                    acc[r][3] = fmaf(a, b.w, acc[r][3]);
                }
            }
        }
        __syncthreads();
    }
    float4 bb = *(const float4*)(bout + col0 + tx * 4);
#pragma unroll
    for (int r = 0; r < 2; ++r)
        *(float4*)(out + (row0 + r) * C_DIM + col0 + tx * 4) =
            make_float4(acc[r][0] + bb.x, acc[r][1] + bb.y, acc[r][2] + bb.z, acc[r][3] + bb.w);
}

extern "C" void kernel_launch(void* const* d_in, const int* in_sizes, int n_in,
                              void* d_out, int out_size, void* d_ws, size_t ws_size,
                              hipStream_t stream) {
    const float* x     = (const float*)d_in[0];
    const float* rot   = (const float*)d_in[1];
    const float* trans = (const float*)d_in[2];
    const float* Wq    = (const float*)d_in[3];
    const float* Wk    = (const float*)d_in[4];
    const float* Wv    = (const float*)d_in[5];
    const float* Wqp   = (const float*)d_in[6];
    const float* Wkp   = (const float*)d_in[7];
    const float* Wvp   = (const float*)d_in[8];
    const float* Wout  = (const float*)d_in[9];
    const float* bout  = (const float*)d_in[10];
    float* out = (float*)d_out;

    float* ws = (float*)d_ws;
    float* Wall = ws;                            // 384*1024
    float* P    = Wall + C_DIM * PCOLS;          // 1024*1024
    float* KVg  = P    + N_TOK * PCOLS;          // 12*60*1024
    float* Qg   = KVg  + H_NUM * KV_ROWS * 1024; // 12*29*1024
    float* qcg  = Qg   + H_NUM * 29 * 1024;      // 12*1024
    float* part = ws;                            // alias Wall+P
    float* att  = Qg;                            // alias Qg (dead after k_attn)

    k_pack<<<384, 256, 0, stream>>>(Wq, Wk, Wv, Wqp, Wkp, Wvp, Wall);
    k_proj<<<dim3(16, 16), 256, 0, stream>>>(x, Wall, P);
    k_prep<<<dim3(8, 12), 256, 0, stream>>>(P, rot, trans, KVg, Qg, qcg);
    k_attn<<<768, 256, 0, stream>>>(KVg, Qg, qcg, part);
    k_comb<<<48, 256, 0, stream>>>(part, rot, trans, att);
    k_out<<<dim3(32, 6), 256, 0, stream>>>(att, Wout, bout, out);
}